// Round 13
// baseline (116.836 us; speedup 1.0000x reference)
//
#include <hip/hip_runtime.h>
#include <hip/hip_bf16.h>

// ---- problem constants ----
#define N_NODES 10000
#define NEDGE   160000
#define ETOT    170000   // edges + self loops
#define GSL     64       // pool accumulator slices (atomic-contention fix)
#define CAP     64       // fixed bucket capacity (max in-degree ~41, P(>=64)~2e-14)

typedef __attribute__((ext_vector_type(4))) float f32x4;
typedef __attribute__((ext_vector_type(8))) short bf16x8;
typedef __attribute__((ext_vector_type(4))) int   int4v;

// f32 -> bf16 bits, round-to-nearest-even
__device__ __forceinline__ unsigned short f2bf(float f) {
    unsigned u = __float_as_uint(f);
    unsigned r = (u + 0x7fffu + ((u >> 16) & 1u)) >> 16;
    return (unsigned short)r;
}
__device__ __forceinline__ float bf2f_lo(unsigned u) {
    return __uint_as_float((u & 0xffffu) << 16);
}
__device__ __forceinline__ float bf2f_hi(unsigned u) {
    return __uint_as_float(u & 0xffff0000u);
}

__device__ __forceinline__ float wred_max(float v) {
#pragma unroll
    for (int o = 32; o; o >>= 1) v = fmaxf(v, __shfl_xor(v, o));
    return v;
}
__device__ __forceinline__ float wred_sum(float v) {
#pragma unroll
    for (int o = 32; o; o >>= 1) v += __shfl_xor(v, o);
    return v;
}

// ---------------- fused prep: transpose W1,W2 | zero scratch ------
// grid = 192 (W1t) + 192 (W2t) + 80 (zero) = 464 blocks of 256.
__global__ __launch_bounds__(256) void prep_kernel(
    const float* __restrict__ W1, unsigned short* __restrict__ w1t,
    const float* __restrict__ W2, unsigned short* __restrict__ w2t,
    float* __restrict__ zreg, int zn) {
    __shared__ float tile[32][33];
    int b = blockIdx.x;
    if (b >= 384) {                      // zero region
        size_t i = (size_t)(b - 384) * 256 + threadIdx.x;
        for (; i < (size_t)zn; i += 80 * 256) zreg[i] = 0.f;
        return;
    }
    // transpose+convert (block-uniform branch selection)
    const float* in; unsigned short* outp; int K, N, bx, by;
    if (b < 192) { int bb = b;       in = W1; outp = w1t; K = 384; N = 512; bx = bb % 16; by = bb / 16; }
    else         { int bb = b - 192; in = W2; outp = w2t; K = 512; N = 384; bx = bb % 12; by = bb / 12; }
    int k0 = by * 32, n0 = bx * 32;
    int tx = threadIdx.x & 31, ty = threadIdx.x >> 5;  // ty 0..7
    for (int i = ty; i < 32; i += 8) {
        int k = k0 + i, n = n0 + tx;
        tile[i][tx] = (k < K && n < N) ? in[(size_t)k * N + n] : 0.f;
    }
    __syncthreads();
    for (int i = ty; i < 32; i += 8) {
        int n = n0 + i, k = k0 + tx;
        if (n < N && k < K) outp[(size_t)n * K + k] = f2bf(tile[tx][i]);
    }
}

// ---------------- bf16 MFMA GEMM + fused attention-logit epilogue ----------------
// Cb[M][N] bf16 = A[M][K] @ Bt[N][K]^T ; AF32: A is f32, converted in-register
// during LDS staging (RNE -> bit-identical to a separate conv pass).
// Also atomically accumulates aals/aald logits from f32 accumulators.
// XCD-aware swizzled 1D grid over gemmBlocks = 8*PPX*NB; extra blocks beyond
// gemmBlocks run the (independent) fixed-bucket CSR scatter when ei != nullptr.
template<bool AF32>
__global__ __launch_bounds__(256) void gemm_mfma(const void* __restrict__ Av,
                                                 const unsigned short* __restrict__ Bt,
                                                 unsigned short* __restrict__ Cb,
                                                 int M, int N, int K,
                                                 const float* __restrict__ avs,
                                                 const float* __restrict__ avd,
                                                 float* __restrict__ aals,
                                                 float* __restrict__ aald,
                                                 int AH, int AC, int NP, int NB,
                                                 int gemmBlocks,
                                                 const int* __restrict__ ei,
                                                 int* __restrict__ cnt,
                                                 int* __restrict__ csr) {
    const int BM = 128, BN = 64, BK = 64;
    __shared__ __align__(16) unsigned short As[BM * BK];  // 16 KB
    __shared__ __align__(16) unsigned short Bs[BN * BK];  // 8 KB
    int b = blockIdx.x;
    if (b >= gemmBlocks) {               // fused fixed-bucket scatter blocks
        int i = (b - gemmBlocks) * 256 + threadIdx.x;
        if (i < ETOT) {
            int s, d;
            if (i < NEDGE) { s = ei[i]; d = ei[NEDGE + i]; } else { s = d = i - NEDGE; }
            int pos = atomicAdd(&cnt[d], 1);
            if (pos < CAP) csr[d * CAP + pos] = s;
        }
        return;
    }
    // ---- XCD swizzle ----
    int xcd = b & 7, rr = b >> 3;
    int jp = rr / NB, cc = rr % NB;
    int panel = xcd + 8 * jp;
    if (panel >= NP) return;
    const int row0 = panel * BM, col0 = cc * BN;

    const int tid = threadIdx.x;
    const int l = tid & 63;
    const int w = tid >> 6;
    const int wr = w >> 1, wc = w & 1;

    f32x4 acc[4][2];
#pragma unroll
    for (int i = 0; i < 4; ++i)
#pragma unroll
        for (int j = 0; j < 2; ++j) acc[i][j] = (f32x4){0.f, 0.f, 0.f, 0.f};

    const int arow = wr * 64 + (l & 15);
    const int brow = wc * 32 + (l & 15);
    const int gbase = l >> 4;

    for (int kt = 0; kt < K; kt += BK) {
#pragma unroll
        for (int it = 0; it < 4; ++it) {
            int s = tid + it * 256;
            int r = s >> 3, p = s & 7;
            int srcp = p ^ (r & 7);
            int gr = row0 + r; if (gr > M - 1) gr = M - 1;
            if constexpr (AF32) {
                const float* Af = (const float*)Av;
                const float* src = Af + (size_t)gr * K + kt + srcp * 8;
                float4 u0 = *(const float4*)(src);
                float4 u1 = *(const float4*)(src + 4);
                unsigned q0 = ((unsigned)f2bf(u0.y) << 16) | f2bf(u0.x);
                unsigned q1 = ((unsigned)f2bf(u0.w) << 16) | f2bf(u0.z);
                unsigned q2 = ((unsigned)f2bf(u1.y) << 16) | f2bf(u1.x);
                unsigned q3 = ((unsigned)f2bf(u1.w) << 16) | f2bf(u1.z);
                int4v v = {(int)q0, (int)q1, (int)q2, (int)q3};
                *(int4v*)(&As[s * 8]) = v;
            } else {
                const unsigned short* Ab = (const unsigned short*)Av;
                int4v v = *(const int4v*)(Ab + (size_t)gr * K + kt + srcp * 8);
                *(int4v*)(&As[s * 8]) = v;
            }
        }
#pragma unroll
        for (int it = 0; it < 2; ++it) {
            int s = tid + it * 256;
            int r = s >> 3, p = s & 7;
            int srcp = p ^ (r & 7);
            int4v v = *(const int4v*)(Bt + (size_t)(col0 + r) * K + kt + srcp * 8);
            *(int4v*)(&Bs[s * 8]) = v;
        }
        __syncthreads();
#pragma unroll
        for (int ks = 0; ks < 2; ++ks) {
            int g = gbase + ks * 4;
            bf16x8 a[4], b2[2];
#pragma unroll
            for (int mi = 0; mi < 4; ++mi) {
                int r = arow + mi * 16;
                a[mi] = *(const bf16x8*)(&As[(r * 8 + (g ^ (r & 7))) * 8]);
            }
#pragma unroll
            for (int ni = 0; ni < 2; ++ni) {
                int r = brow + ni * 16;
                b2[ni] = *(const bf16x8*)(&Bs[(r * 8 + (g ^ (r & 7))) * 8]);
            }
#pragma unroll
            for (int mi = 0; mi < 4; ++mi)
#pragma unroll
                for (int ni = 0; ni < 2; ++ni)
                    acc[mi][ni] = __builtin_amdgcn_mfma_f32_16x16x32_bf16(
                        a[mi], b2[ni], acc[mi][ni], 0, 0, 0);
        }
        __syncthreads();
    }
    // C write (bf16)
#pragma unroll
    for (int mi = 0; mi < 4; ++mi) {
#pragma unroll
        for (int r = 0; r < 4; ++r) {
            int row = row0 + wr * 64 + mi * 16 + (l >> 4) * 4 + r;
            if (row >= M) continue;
#pragma unroll
            for (int ni = 0; ni < 2; ++ni) {
                int col = col0 + wc * 32 + ni * 16 + (l & 15);
                Cb[(size_t)row * N + col] = f2bf(acc[mi][ni][r]);
            }
        }
    }
    // fused logits epilogue
    {
        int hd = col0 / AC;              // block-uniform (BN=64 divides AC)
        int colA = col0 + wc * 32 + (l & 15);
        int colB = colA + 16;
        float asA = avs[colA], asB = avs[colB];
        float adA = avd[colA], adB = avd[colB];
#pragma unroll
        for (int mi = 0; mi < 4; ++mi)
#pragma unroll
            for (int r = 0; r < 4; ++r) {
                int row = row0 + wr * 64 + mi * 16 + (l >> 4) * 4 + r;
                float ps = acc[mi][0][r] * asA + acc[mi][1][r] * asB;
                float pd = acc[mi][0][r] * adA + acc[mi][1][r] * adB;
#pragma unroll
                for (int o = 1; o < 16; o <<= 1) {
                    ps += __shfl_xor(ps, o);
                    pd += __shfl_xor(pd, o);
                }
                if ((l & 15) == 0 && row < M) {
                    atomicAdd(&aals[row * AH + hd], ps);
                    atomicAdd(&aald[row * AH + hd], pd);
                }
            }
    }
}

// -------- layer-1 aggregate: one wave per (node, head), single-chunk softmax
// (deg <= CAP = 64 lanes), 4x-unrolled gather. H=2, C=256.
__global__ __launch_bounds__(256) void node_agg1(
    const int* __restrict__ csr, const int* __restrict__ cnt,
    const float* __restrict__ als, const float* __restrict__ ald,
    const unsigned short* __restrict__ h, const float* __restrict__ bias,
    unsigned short* __restrict__ outB) {
    int wv = threadIdx.x >> 6;
    int d = blockIdx.x * 2 + (wv >> 1);   // grid = N_NODES/2, no partial
    int hd = wv & 1;
    int lane = threadIdx.x & 63;
    int deg = min(cnt[d], CAP);
    int beg = d * CAP;
    float aldh = ald[d * 2 + hd];
    int srcj = 0;
    float e = -3.4e38f;
    if (lane < deg) {
        srcj = csr[beg + lane];
        e = als[srcj * 2 + hd] + aldh;
        e = (e >= 0.f) ? e : 0.2f * e;
    }
    float m = wred_max(e);
    float p = (lane < deg) ? __expf(e - m) : 0.f;
    float s = wred_sum(p);
    float acc[4] = {};
    const unsigned short* hh = h + hd * 256 + lane * 4;
    int jj = 0;
    for (; jj + 4 <= deg; jj += 4) {
        int sA = __shfl(srcj, jj),     sB = __shfl(srcj, jj + 1);
        int sC = __shfl(srcj, jj + 2), sD = __shfl(srcj, jj + 3);
        float wA = __shfl(p, jj),     wB = __shfl(p, jj + 1);
        float wC = __shfl(p, jj + 2), wD = __shfl(p, jj + 3);
        uint2 uA = *(const uint2*)(hh + (size_t)sA * 512);
        uint2 uB = *(const uint2*)(hh + (size_t)sB * 512);
        uint2 uC = *(const uint2*)(hh + (size_t)sC * 512);
        uint2 uD = *(const uint2*)(hh + (size_t)sD * 512);
        acc[0] += bf2f_lo(uA.x) * wA + bf2f_lo(uB.x) * wB +
                  bf2f_lo(uC.x) * wC + bf2f_lo(uD.x) * wD;
        acc[1] += bf2f_hi(uA.x) * wA + bf2f_hi(uB.x) * wB +
                  bf2f_hi(uC.x) * wC + bf2f_hi(uD.x) * wD;
        acc[2] += bf2f_lo(uA.y) * wA + bf2f_lo(uB.y) * wB +
                  bf2f_lo(uC.y) * wC + bf2f_lo(uD.y) * wD;
        acc[3] += bf2f_hi(uA.y) * wA + bf2f_hi(uB.y) * wB +
                  bf2f_hi(uC.y) * wC + bf2f_hi(uD.y) * wD;
    }
    for (; jj < deg; ++jj) {
        int sA = __shfl(srcj, jj);
        float wA = __shfl(p, jj);
        uint2 uA = *(const uint2*)(hh + (size_t)sA * 512);
        acc[0] += bf2f_lo(uA.x) * wA;
        acc[1] += bf2f_hi(uA.x) * wA;
        acc[2] += bf2f_lo(uA.y) * wA;
        acc[3] += bf2f_hi(uA.y) * wA;
    }
    float inv = 1.f / s;
    int c0 = hd * 256 + lane * 4;
    float v0 = acc[0] * inv + bias[c0];
    float v1 = acc[1] * inv + bias[c0 + 1];
    float v2 = acc[2] * inv + bias[c0 + 2];
    float v3 = acc[3] * inv + bias[c0 + 3];
    v0 = v0 > 0.f ? v0 : 0.f;  v1 = v1 > 0.f ? v1 : 0.f;
    v2 = v2 > 0.f ? v2 : 0.f;  v3 = v3 > 0.f ? v3 : 0.f;
    uint2 pk;
    pk.x = ((unsigned)f2bf(v1) << 16) | f2bf(v0);
    pk.y = ((unsigned)f2bf(v3) << 16) | f2bf(v2);
    *(uint2*)(outB + (size_t)d * 512 + c0) = pk;
}

// -------- layer-2 aggregate + fused mean-pool (sliced accumulators),
// single-chunk softmax, 4x unroll. One wave per dst node; grid 2500x4.
__global__ __launch_bounds__(256) void node_agg2(
    const int* __restrict__ csr, const int* __restrict__ cnt,
    const float* __restrict__ als, const float* __restrict__ ald,
    const unsigned short* __restrict__ h, const float* __restrict__ bias,
    float* __restrict__ g_sl) {
    __shared__ float gpart[4][6][64];
    int wv = threadIdx.x >> 6;
    int d = blockIdx.x * 4 + wv;        // grid is exactly N_NODES/4
    int lane = threadIdx.x & 63;
    int deg = min(cnt[d], CAP);
    int beg = d * CAP;
    float ald0 = ald[d];
    int srcj = 0;
    float e0 = -3.4e38f;
    if (lane < deg) {
        srcj = csr[beg + lane];
        e0 = als[srcj] + ald0;
        e0 = (e0 >= 0.f) ? e0 : 0.2f * e0;
    }
    float m0 = wred_max(e0);
    float p0 = (lane < deg) ? __expf(e0 - m0) : 0.f;
    float s0 = wred_sum(p0);
    float acc[6] = {};
    int jj = 0;
    for (; jj + 4 <= deg; jj += 4) {
        int sA = __shfl(srcj, jj),     sB = __shfl(srcj, jj + 1);
        int sC = __shfl(srcj, jj + 2), sD = __shfl(srcj, jj + 3);
        float wA = __shfl(p0, jj),     wB = __shfl(p0, jj + 1);
        float wC = __shfl(p0, jj + 2), wD = __shfl(p0, jj + 3);
        const unsigned* hA = (const unsigned*)(h + (size_t)sA * 384);
        const unsigned* hB = (const unsigned*)(h + (size_t)sB * 384);
        const unsigned* hC = (const unsigned*)(h + (size_t)sC * 384);
        const unsigned* hD = (const unsigned*)(h + (size_t)sD * 384);
#pragma unroll
        for (int it = 0; it < 3; ++it) {
            unsigned a = hA[lane + it * 64], b = hB[lane + it * 64];
            unsigned c = hC[lane + it * 64], e = hD[lane + it * 64];
            acc[2 * it]     += bf2f_lo(a) * wA + bf2f_lo(b) * wB +
                               bf2f_lo(c) * wC + bf2f_lo(e) * wD;
            acc[2 * it + 1] += bf2f_hi(a) * wA + bf2f_hi(b) * wB +
                               bf2f_hi(c) * wC + bf2f_hi(e) * wD;
        }
    }
    for (; jj < deg; ++jj) {
        int sA = __shfl(srcj, jj);
        float wA = __shfl(p0, jj);
        const unsigned* hA = (const unsigned*)(h + (size_t)sA * 384);
#pragma unroll
        for (int it = 0; it < 3; ++it) {
            unsigned ua = hA[lane + it * 64];
            acc[2 * it]     += bf2f_lo(ua) * wA;
            acc[2 * it + 1] += bf2f_hi(ua) * wA;
        }
    }
    float inv = 1.f / s0;
#pragma unroll
    for (int it = 0; it < 3; ++it) {
        int c = (lane + it * 64) * 2;
        float v0 = acc[2 * it] * inv + bias[c];
        float v1 = acc[2 * it + 1] * inv + bias[c + 1];
        v0 = v0 > 0.f ? v0 : 0.f;
        v1 = v1 > 0.f ? v1 : 0.f;
        gpart[wv][2 * it][lane] = v0;
        gpart[wv][2 * it + 1][lane] = v1;
    }
    __syncthreads();
    if (wv == 0) {
        float* gslice = g_sl + (size_t)(blockIdx.x & (GSL - 1)) * 384;
#pragma unroll
        for (int q = 0; q < 6; ++q) {
            float sum = gpart[0][q][lane] + gpart[1][q][lane] +
                        gpart[2][q][lane] + gpart[3][q][lane];
            int c = (lane + (q >> 1) * 64) * 2 + (q & 1);
            atomicAdd(&gslice[c], sum);
        }
    }
}

// -------- fused final: y = (sum slices /N) @ Wl + bl, then last block normalizes.
__global__ __launch_bounds__(256) void final_fused(const float* __restrict__ g_sl,
                                                   const float* __restrict__ Wl,
                                                   const float* __restrict__ bl,
                                                   float* __restrict__ yv,
                                                   int* __restrict__ ticket,
                                                   float* __restrict__ out) {
    __shared__ float gs[384];
    __shared__ float red[8][32];
    __shared__ int lastFlag;
    int t = threadIdx.x;
    for (int k = t; k < 384; k += 256) {
        float v = 0.f;
        for (int s = 0; s < GSL; ++s) v += g_sl[(size_t)s * 384 + k];
        gs[k] = v * (1.f / (float)N_NODES);
    }
    __syncthreads();
    int col = blockIdx.x * 32 + (t & 31);
    int ks = t >> 5;                     // 0..7, 48 k each
    float yp = 0.f;
    for (int k = ks * 48; k < ks * 48 + 48; ++k)
        yp += gs[k] * Wl[(size_t)k * 384 + col];
    red[ks][t & 31] = yp;
    __syncthreads();
    if (t < 32) {
        float y = bl[blockIdx.x * 32 + t];
#pragma unroll
        for (int q = 0; q < 8; ++q) y += red[q][t];
        yv[blockIdx.x * 32 + t] = y;
    }
    __threadfence();
    __syncthreads();
    if (t == 0) lastFlag = (atomicAdd(ticket, 1) == 11);
    __syncthreads();
    if (!lastFlag) return;
    __threadfence();
    float y0 = __hip_atomic_load(&yv[t], __ATOMIC_RELAXED, __HIP_MEMORY_SCOPE_AGENT);
    float y1 = (t < 128)
        ? __hip_atomic_load(&yv[256 + t], __ATOMIC_RELAXED, __HIP_MEMORY_SCOPE_AGENT)
        : 0.f;
    float sq = y0 * y0 + y1 * y1;
    for (int o = 32; o; o >>= 1) sq += __shfl_xor(sq, o);
    if ((t & 63) == 0) red[0][t >> 6] = sq;
    __syncthreads();
    float tot = red[0][0] + red[0][1] + red[0][2] + red[0][3];
    float inv = 1.f / fmaxf(sqrtf(tot), 1e-12f);
    out[t] = y0 * inv;
    if (t < 128) out[256 + t] = y1 * inv;
}

extern "C" void kernel_launch(void* const* d_in, const int* in_sizes, int n_in,
                              void* d_out, int out_size, void* d_ws, size_t ws_size,
                              hipStream_t stream) {
    const float* x   = (const float*)d_in[0];
    const int*   ei  = (const int*)d_in[1];
    const float* W1  = (const float*)d_in[2];
    const float* as1 = (const float*)d_in[3];
    const float* ad1 = (const float*)d_in[4];
    const float* b1  = (const float*)d_in[5];
    const float* W2  = (const float*)d_in[6];
    const float* as2 = (const float*)d_in[7];
    const float* ad2 = (const float*)d_in[8];
    const float* b2  = (const float*)d_in[9];
    const float* Wl  = (const float*)d_in[10];
    const float* bl  = (const float*)d_in[11];
    float* out = (float*)d_out;
    float* ws  = (float*)d_ws;

    // ---- workspace layout (float units) ----
    unsigned short* h1b   = (unsigned short*)ws;              // 5,120,000 sh (h2b aliases)
    unsigned short* h2b   = h1b;
    unsigned short* agg1b = (unsigned short*)(ws + 2560000);  // 5,120,000 sh
    unsigned short* w1t   = (unsigned short*)(ws + 7040000);  // 196,608 sh
    unsigned short* w2t   = (unsigned short*)(ws + 7138304);  // 196,608 sh
    // zero region (contiguous):
    float* zreg = ws + 7236608;
    float* als1 = zreg;                     // 20,000
    float* ald1 = als1 + 20000;             // 20,000
    float* als2 = ald1 + 20000;             // 10,000
    float* ald2 = als2 + 10000;             // 10,000
    float* g_sl = ald2 + 10000;             // GSL*384 = 24,576
    int*   cnt  = (int*)(g_sl + GSL * 384); // 10,000
    int*   ticket = cnt + 10000;            // 16 (1 used, padded)
    const int ZN = 20000 + 20000 + 10000 + 10000 + GSL * 384 + 10000 + 16; // 94,592
    int*   csr  = (int*)(zreg + ZN);        // N_NODES*CAP = 640,000
    float* yv   = (float*)(csr + N_NODES * CAP);  // 384

    const int EBLK = (ETOT + 255) / 256;   // 665
    const int NP = (N_NODES + 127) / 128;  // 79 row panels
    const int PPX = (NP + 7) / 8;          // 10 panels per XCD

    // 1. prep: transpose W1/W2, zero scratch (incl. cnt + ticket)
    prep_kernel<<<464, 256, 0, stream>>>(W1, w1t, W2, w2t, zreg, ZN);

    // 2. layer 1 GEMM, A = f32 x converted in-register
    //    (+ fused logits + fused fixed-bucket scatter): H=2, C=256, NB=8
    {
        int gemmBlocks = 8 * PPX * 8;  // 640
        gemm_mfma<true><<<gemmBlocks + EBLK, 256, 0, stream>>>(
            x, w1t, h1b, N_NODES, 512, 384, as1, ad1, als1, ald1, 2, 256, NP, 8,
            gemmBlocks, ei, cnt, csr);
    }
    // 3. layer 1 aggregate (wave per node-head)
    node_agg1<<<N_NODES / 2, 256, 0, stream>>>(csr, cnt, als1, ald1, h1b, b1, agg1b);

    // 4. layer 2 GEMM, A = bf16 agg1b (+ fused logits): H=1, C=384, NB=6
    {
        int gemmBlocks = 8 * PPX * 6;  // 480
        gemm_mfma<false><<<gemmBlocks, 256, 0, stream>>>(
            agg1b, w2t, h2b, N_NODES, 384, 512, as2, ad2, als2, ald2, 1, 384, NP, 6,
            gemmBlocks, nullptr, cnt, csr);
    }
    // 5. layer 2 aggregate + fused mean pool (sliced)
    node_agg2<<<N_NODES / 4, 256, 0, stream>>>(csr, cnt, als2, ald2, h2b, b2, g_sl);

    // 6. fused final linear + last-block normalize
    final_fused<<<12, 256, 0, stream>>>(g_sl, Wl, bl, yv, ticket, out);
}

// Round 14
// 107.219 us; speedup vs baseline: 1.0897x; 1.0897x over previous
//
#include <hip/hip_runtime.h>
#include <hip/hip_bf16.h>

// ---- problem constants ----
#define N_NODES 10000
#define NEDGE   160000
#define ETOT    170000   // edges + self loops
#define GSL     64       // pool accumulator slices (atomic-contention fix)
#define CAP     64       // fixed bucket capacity (max in-degree ~41, P(>=64)~2e-14)

typedef __attribute__((ext_vector_type(4))) float f32x4;
typedef __attribute__((ext_vector_type(8))) short bf16x8;
typedef __attribute__((ext_vector_type(4))) int   int4v;

// f32 -> bf16 bits, round-to-nearest-even
__device__ __forceinline__ unsigned short f2bf(float f) {
    unsigned u = __float_as_uint(f);
    unsigned r = (u + 0x7fffu + ((u >> 16) & 1u)) >> 16;
    return (unsigned short)r;
}
__device__ __forceinline__ float bf2f_lo(unsigned u) {
    return __uint_as_float((u & 0xffffu) << 16);
}
__device__ __forceinline__ float bf2f_hi(unsigned u) {
    return __uint_as_float(u & 0xffff0000u);
}

__device__ __forceinline__ float wred_max(float v) {
#pragma unroll
    for (int o = 32; o; o >>= 1) v = fmaxf(v, __shfl_xor(v, o));
    return v;
}
__device__ __forceinline__ float wred_sum(float v) {
#pragma unroll
    for (int o = 32; o; o >>= 1) v += __shfl_xor(v, o);
    return v;
}

// ---------------- fused prep: conv x->bf16 | transpose W1,W2 | zero scratch ------
// grid = 3750 (conv) + 192 (W1t) + 192 (W2t) + 80 (zero) = 4214 blocks of 256.
// The wide conv pass also absorbs cold-HBM first-touch of x each graph replay.
__global__ __launch_bounds__(256) void prep_kernel(
    const float* __restrict__ x, unsigned short* __restrict__ xb,
    const float* __restrict__ W1, unsigned short* __restrict__ w1t,
    const float* __restrict__ W2, unsigned short* __restrict__ w2t,
    float* __restrict__ zreg, int zn) {
    __shared__ float tile[32][33];
    int b = blockIdx.x;
    if (b < 3750) {                      // conv: 3750*256*4 = 3,840,000 elements
        int i = (b * 256 + threadIdx.x) * 4;
        float4 v = *(const float4*)(x + i);
        unsigned u01 = ((unsigned)f2bf(v.y) << 16) | f2bf(v.x);
        unsigned u23 = ((unsigned)f2bf(v.w) << 16) | f2bf(v.z);
        uint2 pk = {u01, u23};
        *(uint2*)(xb + i) = pk;
        return;
    }
    if (b >= 4134) {                     // zero region
        size_t i = (size_t)(b - 4134) * 256 + threadIdx.x;
        for (; i < (size_t)zn; i += 80 * 256) zreg[i] = 0.f;
        return;
    }
    // transpose+convert (block-uniform branch selection)
    const float* in; unsigned short* outp; int K, N, bx, by;
    if (b < 3942) { int bb = b - 3750; in = W1; outp = w1t; K = 384; N = 512; bx = bb % 16; by = bb / 16; }
    else          { int bb = b - 3942; in = W2; outp = w2t; K = 512; N = 384; bx = bb % 12; by = bb / 12; }
    int k0 = by * 32, n0 = bx * 32;
    int tx = threadIdx.x & 31, ty = threadIdx.x >> 5;  // ty 0..7
    for (int i = ty; i < 32; i += 8) {
        int k = k0 + i, n = n0 + tx;
        tile[i][tx] = (k < K && n < N) ? in[(size_t)k * N + n] : 0.f;
    }
    __syncthreads();
    for (int i = ty; i < 32; i += 8) {
        int n = n0 + i, k = k0 + tx;
        if (n < K * 0 + N && k < K) outp[(size_t)n * K + k] = f2bf(tile[tx][i]);
    }
}

// ---------------- bf16 MFMA GEMM + fused attention-logit epilogue ----------------
// Cb[M][N] bf16 = A[M][K] @ Bt[N][K]^T ; also atomically accumulates
// aals[row*AH+hd] += sum_col acc*avs[col], aald likewise (f32, pre-rounding).
// XCD-aware swizzled 1D grid over gemmBlocks = 8*PPX*NB; extra blocks beyond
// gemmBlocks run the (independent) fixed-bucket CSR scatter when ei != nullptr.
__global__ __launch_bounds__(256) void gemm_mfma(const unsigned short* __restrict__ A,
                                                 const unsigned short* __restrict__ Bt,
                                                 unsigned short* __restrict__ Cb,
                                                 int M, int N, int K,
                                                 const float* __restrict__ avs,
                                                 const float* __restrict__ avd,
                                                 float* __restrict__ aals,
                                                 float* __restrict__ aald,
                                                 int AH, int AC, int NP, int NB,
                                                 int gemmBlocks,
                                                 const int* __restrict__ ei,
                                                 int* __restrict__ cnt,
                                                 int* __restrict__ csr) {
    const int BM = 128, BN = 64, BK = 64;
    __shared__ __align__(16) unsigned short As[BM * BK];  // 16 KB
    __shared__ __align__(16) unsigned short Bs[BN * BK];  // 8 KB
    int b = blockIdx.x;
    if (b >= gemmBlocks) {               // fused fixed-bucket scatter blocks
        int i = (b - gemmBlocks) * 256 + threadIdx.x;
        if (i < ETOT) {
            int s, d;
            if (i < NEDGE) { s = ei[i]; d = ei[NEDGE + i]; } else { s = d = i - NEDGE; }
            int pos = atomicAdd(&cnt[d], 1);
            if (pos < CAP) csr[d * CAP + pos] = s;
        }
        return;
    }
    // ---- XCD swizzle ----
    int xcd = b & 7, rr = b >> 3;
    int jp = rr / NB, cc = rr % NB;
    int panel = xcd + 8 * jp;
    if (panel >= NP) return;
    const int row0 = panel * BM, col0 = cc * BN;

    const int tid = threadIdx.x;
    const int l = tid & 63;
    const int w = tid >> 6;
    const int wr = w >> 1, wc = w & 1;

    f32x4 acc[4][2];
#pragma unroll
    for (int i = 0; i < 4; ++i)
#pragma unroll
        for (int j = 0; j < 2; ++j) acc[i][j] = (f32x4){0.f, 0.f, 0.f, 0.f};

    const int arow = wr * 64 + (l & 15);
    const int brow = wc * 32 + (l & 15);
    const int gbase = l >> 4;

    for (int kt = 0; kt < K; kt += BK) {
#pragma unroll
        for (int it = 0; it < 4; ++it) {
            int s = tid + it * 256;
            int r = s >> 3, p = s & 7;
            int srcp = p ^ (r & 7);
            int gr = row0 + r; if (gr > M - 1) gr = M - 1;
            int4v v = *(const int4v*)(A + (size_t)gr * K + kt + srcp * 8);
            *(int4v*)(&As[s * 8]) = v;
        }
#pragma unroll
        for (int it = 0; it < 2; ++it) {
            int s = tid + it * 256;
            int r = s >> 3, p = s & 7;
            int srcp = p ^ (r & 7);
            int4v v = *(const int4v*)(Bt + (size_t)(col0 + r) * K + kt + srcp * 8);
            *(int4v*)(&Bs[s * 8]) = v;
        }
        __syncthreads();
#pragma unroll
        for (int ks = 0; ks < 2; ++ks) {
            int g = gbase + ks * 4;
            bf16x8 a[4], b2[2];
#pragma unroll
            for (int mi = 0; mi < 4; ++mi) {
                int r = arow + mi * 16;
                a[mi] = *(const bf16x8*)(&As[(r * 8 + (g ^ (r & 7))) * 8]);
            }
#pragma unroll
            for (int ni = 0; ni < 2; ++ni) {
                int r = brow + ni * 16;
                b2[ni] = *(const bf16x8*)(&Bs[(r * 8 + (g ^ (r & 7))) * 8]);
            }
#pragma unroll
            for (int mi = 0; mi < 4; ++mi)
#pragma unroll
                for (int ni = 0; ni < 2; ++ni)
                    acc[mi][ni] = __builtin_amdgcn_mfma_f32_16x16x32_bf16(
                        a[mi], b2[ni], acc[mi][ni], 0, 0, 0);
        }
        __syncthreads();
    }
    // C write (bf16)
#pragma unroll
    for (int mi = 0; mi < 4; ++mi) {
#pragma unroll
        for (int r = 0; r < 4; ++r) {
            int row = row0 + wr * 64 + mi * 16 + (l >> 4) * 4 + r;
            if (row >= M) continue;
#pragma unroll
            for (int ni = 0; ni < 2; ++ni) {
                int col = col0 + wc * 32 + ni * 16 + (l & 15);
                Cb[(size_t)row * N + col] = f2bf(acc[mi][ni][r]);
            }
        }
    }
    // fused logits epilogue
    {
        int hd = col0 / AC;              // block-uniform (BN=64 divides AC)
        int colA = col0 + wc * 32 + (l & 15);
        int colB = colA + 16;
        float asA = avs[colA], asB = avs[colB];
        float adA = avd[colA], adB = avd[colB];
#pragma unroll
        for (int mi = 0; mi < 4; ++mi)
#pragma unroll
            for (int r = 0; r < 4; ++r) {
                int row = row0 + wr * 64 + mi * 16 + (l >> 4) * 4 + r;
                float ps = acc[mi][0][r] * asA + acc[mi][1][r] * asB;
                float pd = acc[mi][0][r] * adA + acc[mi][1][r] * adB;
#pragma unroll
                for (int o = 1; o < 16; o <<= 1) {
                    ps += __shfl_xor(ps, o);
                    pd += __shfl_xor(pd, o);
                }
                if ((l & 15) == 0 && row < M) {
                    atomicAdd(&aals[row * AH + hd], ps);
                    atomicAdd(&aald[row * AH + hd], pd);
                }
            }
    }
}

// -------- layer-1 aggregate: one wave per (node, head), single-chunk softmax
// (deg <= CAP = 64 lanes), 4x-unrolled gather. H=2, C=256.
__global__ __launch_bounds__(256) void node_agg1(
    const int* __restrict__ csr, const int* __restrict__ cnt,
    const float* __restrict__ als, const float* __restrict__ ald,
    const unsigned short* __restrict__ h, const float* __restrict__ bias,
    unsigned short* __restrict__ outB) {
    int wv = threadIdx.x >> 6;
    int d = blockIdx.x * 2 + (wv >> 1);   // grid = N_NODES/2, no partial
    int hd = wv & 1;
    int lane = threadIdx.x & 63;
    int deg = min(cnt[d], CAP);
    int beg = d * CAP;
    float aldh = ald[d * 2 + hd];
    int srcj = 0;
    float e = -3.4e38f;
    if (lane < deg) {
        srcj = csr[beg + lane];
        e = als[srcj * 2 + hd] + aldh;
        e = (e >= 0.f) ? e : 0.2f * e;
    }
    float m = wred_max(e);
    float p = (lane < deg) ? __expf(e - m) : 0.f;
    float s = wred_sum(p);
    float acc[4] = {};
    const unsigned short* hh = h + hd * 256 + lane * 4;
    int jj = 0;
    for (; jj + 4 <= deg; jj += 4) {
        int sA = __shfl(srcj, jj),     sB = __shfl(srcj, jj + 1);
        int sC = __shfl(srcj, jj + 2), sD = __shfl(srcj, jj + 3);
        float wA = __shfl(p, jj),     wB = __shfl(p, jj + 1);
        float wC = __shfl(p, jj + 2), wD = __shfl(p, jj + 3);
        uint2 uA = *(const uint2*)(hh + (size_t)sA * 512);
        uint2 uB = *(const uint2*)(hh + (size_t)sB * 512);
        uint2 uC = *(const uint2*)(hh + (size_t)sC * 512);
        uint2 uD = *(const uint2*)(hh + (size_t)sD * 512);
        acc[0] += bf2f_lo(uA.x) * wA + bf2f_lo(uB.x) * wB +
                  bf2f_lo(uC.x) * wC + bf2f_lo(uD.x) * wD;
        acc[1] += bf2f_hi(uA.x) * wA + bf2f_hi(uB.x) * wB +
                  bf2f_hi(uC.x) * wC + bf2f_hi(uD.x) * wD;
        acc[2] += bf2f_lo(uA.y) * wA + bf2f_lo(uB.y) * wB +
                  bf2f_lo(uC.y) * wC + bf2f_lo(uD.y) * wD;
        acc[3] += bf2f_hi(uA.y) * wA + bf2f_hi(uB.y) * wB +
                  bf2f_hi(uC.y) * wC + bf2f_hi(uD.y) * wD;
    }
    for (; jj < deg; ++jj) {
        int sA = __shfl(srcj, jj);
        float wA = __shfl(p, jj);
        uint2 uA = *(const uint2*)(hh + (size_t)sA * 512);
        acc[0] += bf2f_lo(uA.x) * wA;
        acc[1] += bf2f_hi(uA.x) * wA;
        acc[2] += bf2f_lo(uA.y) * wA;
        acc[3] += bf2f_hi(uA.y) * wA;
    }
    float inv = 1.f / s;
    int c0 = hd * 256 + lane * 4;
    float v0 = acc[0] * inv + bias[c0];
    float v1 = acc[1] * inv + bias[c0 + 1];
    float v2 = acc[2] * inv + bias[c0 + 2];
    float v3 = acc[3] * inv + bias[c0 + 3];
    v0 = v0 > 0.f ? v0 : 0.f;  v1 = v1 > 0.f ? v1 : 0.f;
    v2 = v2 > 0.f ? v2 : 0.f;  v3 = v3 > 0.f ? v3 : 0.f;
    uint2 pk;
    pk.x = ((unsigned)f2bf(v1) << 16) | f2bf(v0);
    pk.y = ((unsigned)f2bf(v3) << 16) | f2bf(v2);
    *(uint2*)(outB + (size_t)d * 512 + c0) = pk;
}

// -------- layer-2 aggregate + fused mean-pool (sliced accumulators),
// single-chunk softmax, 4x unroll. One wave per dst node; grid 2500x4.
__global__ __launch_bounds__(256) void node_agg2(
    const int* __restrict__ csr, const int* __restrict__ cnt,
    const float* __restrict__ als, const float* __restrict__ ald,
    const unsigned short* __restrict__ h, const float* __restrict__ bias,
    float* __restrict__ g_sl) {
    __shared__ float gpart[4][6][64];
    int wv = threadIdx.x >> 6;
    int d = blockIdx.x * 4 + wv;        // grid is exactly N_NODES/4
    int lane = threadIdx.x & 63;
    int deg = min(cnt[d], CAP);
    int beg = d * CAP;
    float ald0 = ald[d];
    int srcj = 0;
    float e0 = -3.4e38f;
    if (lane < deg) {
        srcj = csr[beg + lane];
        e0 = als[srcj] + ald0;
        e0 = (e0 >= 0.f) ? e0 : 0.2f * e0;
    }
    float m0 = wred_max(e0);
    float p0 = (lane < deg) ? __expf(e0 - m0) : 0.f;
    float s0 = wred_sum(p0);
    float acc[6] = {};
    int jj = 0;
    for (; jj + 4 <= deg; jj += 4) {
        int sA = __shfl(srcj, jj),     sB = __shfl(srcj, jj + 1);
        int sC = __shfl(srcj, jj + 2), sD = __shfl(srcj, jj + 3);
        float wA = __shfl(p0, jj),     wB = __shfl(p0, jj + 1);
        float wC = __shfl(p0, jj + 2), wD = __shfl(p0, jj + 3);
        const unsigned* hA = (const unsigned*)(h + (size_t)sA * 384);
        const unsigned* hB = (const unsigned*)(h + (size_t)sB * 384);
        const unsigned* hC = (const unsigned*)(h + (size_t)sC * 384);
        const unsigned* hD = (const unsigned*)(h + (size_t)sD * 384);
#pragma unroll
        for (int it = 0; it < 3; ++it) {
            unsigned a = hA[lane + it * 64], b = hB[lane + it * 64];
            unsigned c = hC[lane + it * 64], e = hD[lane + it * 64];
            acc[2 * it]     += bf2f_lo(a) * wA + bf2f_lo(b) * wB +
                               bf2f_lo(c) * wC + bf2f_lo(e) * wD;
            acc[2 * it + 1] += bf2f_hi(a) * wA + bf2f_hi(b) * wB +
                               bf2f_hi(c) * wC + bf2f_hi(e) * wD;
        }
    }
    for (; jj < deg; ++jj) {
        int sA = __shfl(srcj, jj);
        float wA = __shfl(p0, jj);
        const unsigned* hA = (const unsigned*)(h + (size_t)sA * 384);
#pragma unroll
        for (int it = 0; it < 3; ++it) {
            unsigned ua = hA[lane + it * 64];
            acc[2 * it]     += bf2f_lo(ua) * wA;
            acc[2 * it + 1] += bf2f_hi(ua) * wA;
        }
    }
    float inv = 1.f / s0;
#pragma unroll
    for (int it = 0; it < 3; ++it) {
        int c = (lane + it * 64) * 2;
        float v0 = acc[2 * it] * inv + bias[c];
        float v1 = acc[2 * it + 1] * inv + bias[c + 1];
        v0 = v0 > 0.f ? v0 : 0.f;
        v1 = v1 > 0.f ? v1 : 0.f;
        gpart[wv][2 * it][lane] = v0;
        gpart[wv][2 * it + 1][lane] = v1;
    }
    __syncthreads();
    if (wv == 0) {
        float* gslice = g_sl + (size_t)(blockIdx.x & (GSL - 1)) * 384;
#pragma unroll
        for (int q = 0; q < 6; ++q) {
            float sum = gpart[0][q][lane] + gpart[1][q][lane] +
                        gpart[2][q][lane] + gpart[3][q][lane];
            int c = (lane + (q >> 1) * 64) * 2 + (q & 1);
            atomicAdd(&gslice[c], sum);
        }
    }
}

// -------- fused final: y = (sum slices /N) @ Wl + bl, then last block normalizes.
__global__ __launch_bounds__(256) void final_fused(const float* __restrict__ g_sl,
                                                   const float* __restrict__ Wl,
                                                   const float* __restrict__ bl,
                                                   float* __restrict__ yv,
                                                   int* __restrict__ ticket,
                                                   float* __restrict__ out) {
    __shared__ float gs[384];
    __shared__ float red[8][32];
    __shared__ int lastFlag;
    int t = threadIdx.x;
    for (int k = t; k < 384; k += 256) {
        float v = 0.f;
        for (int s = 0; s < GSL; ++s) v += g_sl[(size_t)s * 384 + k];
        gs[k] = v * (1.f / (float)N_NODES);
    }
    __syncthreads();
    int col = blockIdx.x * 32 + (t & 31);
    int ks = t >> 5;                     // 0..7, 48 k each
    float yp = 0.f;
    for (int k = ks * 48; k < ks * 48 + 48; ++k)
        yp += gs[k] * Wl[(size_t)k * 384 + col];
    red[ks][t & 31] = yp;
    __syncthreads();
    if (t < 32) {
        float y = bl[blockIdx.x * 32 + t];
#pragma unroll
        for (int q = 0; q < 8; ++q) y += red[q][t];
        yv[blockIdx.x * 32 + t] = y;
    }
    __threadfence();
    __syncthreads();
    if (t == 0) lastFlag = (atomicAdd(ticket, 1) == 11);
    __syncthreads();
    if (!lastFlag) return;
    __threadfence();
    float y0 = __hip_atomic_load(&yv[t], __ATOMIC_RELAXED, __HIP_MEMORY_SCOPE_AGENT);
    float y1 = (t < 128)
        ? __hip_atomic_load(&yv[256 + t], __ATOMIC_RELAXED, __HIP_MEMORY_SCOPE_AGENT)
        : 0.f;
    float sq = y0 * y0 + y1 * y1;
    for (int o = 32; o; o >>= 1) sq += __shfl_xor(sq, o);
    if ((t & 63) == 0) red[0][t >> 6] = sq;
    __syncthreads();
    float tot = red[0][0] + red[0][1] + red[0][2] + red[0][3];
    float inv = 1.f / fmaxf(sqrtf(tot), 1e-12f);
    out[t] = y0 * inv;
    if (t < 128) out[256 + t] = y1 * inv;
}

extern "C" void kernel_launch(void* const* d_in, const int* in_sizes, int n_in,
                              void* d_out, int out_size, void* d_ws, size_t ws_size,
                              hipStream_t stream) {
    const float* x   = (const float*)d_in[0];
    const int*   ei  = (const int*)d_in[1];
    const float* W1  = (const float*)d_in[2];
    const float* as1 = (const float*)d_in[3];
    const float* ad1 = (const float*)d_in[4];
    const float* b1  = (const float*)d_in[5];
    const float* W2  = (const float*)d_in[6];
    const float* as2 = (const float*)d_in[7];
    const float* ad2 = (const float*)d_in[8];
    const float* b2  = (const float*)d_in[9];
    const float* Wl  = (const float*)d_in[10];
    const float* bl  = (const float*)d_in[11];
    float* out = (float*)d_out;
    float* ws  = (float*)d_ws;

    // ---- workspace layout (float units) ----
    unsigned short* h1b   = (unsigned short*)ws;              // 5,120,000 sh (h2b aliases)
    unsigned short* h2b   = h1b;
    unsigned short* agg1b = (unsigned short*)(ws + 2560000);  // 5,120,000 sh
    unsigned short* xb    = (unsigned short*)(ws + 5120000);  // 3,840,000 sh
    unsigned short* w1t   = (unsigned short*)(ws + 7040000);  // 196,608 sh
    unsigned short* w2t   = (unsigned short*)(ws + 7138304);  // 196,608 sh
    // zero region (contiguous):
    float* zreg = ws + 7236608;
    float* als1 = zreg;                     // 20,000
    float* ald1 = als1 + 20000;             // 20,000
    float* als2 = ald1 + 20000;             // 10,000
    float* ald2 = als2 + 10000;             // 10,000
    float* g_sl = ald2 + 10000;             // GSL*384 = 24,576
    int*   cnt  = (int*)(g_sl + GSL * 384); // 10,000
    int*   ticket = cnt + 10000;            // 16 (1 used, padded)
    const int ZN = 20000 + 20000 + 10000 + 10000 + GSL * 384 + 10000 + 16; // 94,592
    int*   csr  = (int*)(zreg + ZN);        // N_NODES*CAP = 640,000
    float* yv   = (float*)(csr + N_NODES * CAP);  // 384

    const int EBLK = (ETOT + 255) / 256;   // 665
    const int NP = (N_NODES + 127) / 128;  // 79 row panels
    const int PPX = (NP + 7) / 8;          // 10 panels per XCD

    // 1. prep: conv x->bf16, transpose W1/W2, zero scratch (incl. cnt + ticket)
    prep_kernel<<<4214, 256, 0, stream>>>(x, xb, W1, w1t, W2, w2t, zreg, ZN);

    // 2. layer 1 GEMM (+ fused logits + fused fixed-bucket scatter): H=2, C=256, NB=8
    {
        int gemmBlocks = 8 * PPX * 8;  // 640
        gemm_mfma<<<gemmBlocks + EBLK, 256, 0, stream>>>(
            xb, w1t, h1b, N_NODES, 512, 384, as1, ad1, als1, ald1, 2, 256, NP, 8,
            gemmBlocks, ei, cnt, csr);
    }
    // 3. layer 1 aggregate (wave per node-head)
    node_agg1<<<N_NODES / 2, 256, 0, stream>>>(csr, cnt, als1, ald1, h1b, b1, agg1b);

    // 4. layer 2 GEMM (+ fused logits): H=1, C=384, NB=6
    {
        int gemmBlocks = 8 * PPX * 6;  // 480
        gemm_mfma<<<gemmBlocks, 256, 0, stream>>>(
            agg1b, w2t, h2b, N_NODES, 384, 512, as2, ad2, als2, ald2, 1, 384, NP, 6,
            gemmBlocks, nullptr, cnt, csr);
    }
    // 5. layer 2 aggregate + fused mean pool (sliced)
    node_agg2<<<N_NODES / 4, 256, 0, stream>>>(csr, cnt, als2, ald2, h2b, b2, g_sl);

    // 6. fused final linear + last-block normalize
    final_fused<<<12, 256, 0, stream>>>(g_sl, Wl, bl, yv, ticket, out);
}